// Round 1
// baseline (234.050 us; speedup 1.0000x reference)
//
#include <hip/hip_runtime.h>
#include <cstdint>
#include <cstddef>

// NetGrad: J_b = W5 D4 W4 D3 W3 D2 W2 D1 W1  per sample b, output [B,3,64].
// Strategy: forward pass stores G_i = elu'(pre_i) [B,256]; backward accumulates
// the 3-row chain as flat GEMMs [24576,256]x[256,N] with column scaling.
// All fp32 (no fp32 MFMA on CDNA4 -> vector ALU GEMM, 4x4 reg tile, LDS staged).

#define TB 256
#define BM 64
#define BN 64
#define BK 32

constexpr int Bsz = 8192;
constexpr int D   = 256;
constexpr int M3  = Bsz * 3;   // 24576 flattened backward rows

// ---------------- forward layer: Pre = Hin @ W^T + bias; G = elu'(Pre); Hout = elu(Pre)
// Hin [M,K] row-major, W [256,K] row-major (out,in). Grid = (M/BM)*(256/BN).
template<int K, bool WRITE_H>
__global__ __launch_bounds__(TB)
void fwd_kernel(const float* __restrict__ Hin, const float* __restrict__ W,
                const float* __restrict__ bias, float* __restrict__ G,
                float* __restrict__ Hout)
{
    __shared__ float Ht[BK][BM + 4];   // transposed: Ht[k][s]
    __shared__ float Wt[BK][BN + 4];   // transposed: Wt[k][n]
    const int nt = blockIdx.x & 3;     // 256/BN == 4 n-tiles
    const int mt = blockIdx.x >> 2;
    const int m0 = mt * BM, n0 = nt * BN;
    const int tid  = threadIdx.x;
    const int trow = (tid >> 4) << 2;  // 0..60
    const int tcol = (tid & 15) << 2;  // 0..60
    float acc[4][4] = {};

    for (int k0 = 0; k0 < K; k0 += BK) {
        #pragma unroll
        for (int t = 0; t < 2; ++t) {
            const int f4  = tid + t * TB;       // 0..511
            const int row = f4 >> 3;            // 0..63
            const int c   = (f4 & 7) << 2;      // 0..28
            const float4 hv = *(const float4*)(Hin + (size_t)(m0 + row) * K + k0 + c);
            Ht[c + 0][row] = hv.x; Ht[c + 1][row] = hv.y;
            Ht[c + 2][row] = hv.z; Ht[c + 3][row] = hv.w;
            const float4 wv = *(const float4*)(W + (size_t)(n0 + row) * K + k0 + c);
            Wt[c + 0][row] = wv.x; Wt[c + 1][row] = wv.y;
            Wt[c + 2][row] = wv.z; Wt[c + 3][row] = wv.w;
        }
        __syncthreads();
        #pragma unroll
        for (int kk = 0; kk < BK; ++kk) {
            const float4 av = *(const float4*)&Ht[kk][trow];
            const float4 bv = *(const float4*)&Wt[kk][tcol];
            const float a[4] = {av.x, av.y, av.z, av.w};
            const float b[4] = {bv.x, bv.y, bv.z, bv.w};
            #pragma unroll
            for (int r = 0; r < 4; ++r)
                #pragma unroll
                for (int c = 0; c < 4; ++c)
                    acc[r][c] = fmaf(a[r], b[c], acc[r][c]);
        }
        __syncthreads();
    }

    const float4 bsv = *(const float4*)(bias + n0 + tcol);
    const float bb[4] = {bsv.x, bsv.y, bsv.z, bsv.w};
    #pragma unroll
    for (int r = 0; r < 4; ++r) {
        const int m = m0 + trow + r;
        float4 g, h;
        float pre;
        pre = acc[r][0] + bb[0]; if (pre > 0.f) { g.x = 1.f; h.x = pre; } else { g.x = __expf(pre); h.x = g.x - 1.f; }
        pre = acc[r][1] + bb[1]; if (pre > 0.f) { g.y = 1.f; h.y = pre; } else { g.y = __expf(pre); h.y = g.y - 1.f; }
        pre = acc[r][2] + bb[2]; if (pre > 0.f) { g.z = 1.f; h.z = pre; } else { g.z = __expf(pre); h.z = g.z - 1.f; }
        pre = acc[r][3] + bb[3]; if (pre > 0.f) { g.w = 1.f; h.w = pre; } else { g.w = __expf(pre); h.w = g.w - 1.f; }
        *(float4*)(G + (size_t)m * D + n0 + tcol) = g;
        if constexpr (WRITE_H)
            *(float4*)(Hout + (size_t)m * D + n0 + tcol) = h;
    }
}

// ---------------- expand: A[b*3+o, k] = W5[o,k] * G4[b,k]
__global__ __launch_bounds__(TB)
void expand_kernel(const float* __restrict__ G4, const float* __restrict__ W5,
                   float* __restrict__ A)
{
    const int idx = blockIdx.x * TB + threadIdx.x;   // over M3*64 float4s
    const int m = idx >> 6;
    const int k = (idx & 63) << 2;
    if (m >= M3) return;
    const int b = m / 3;
    const int o = m - b * 3;
    const float4 g = *(const float4*)(G4 + (size_t)b * D + k);
    const float4 w = *(const float4*)(W5 + (size_t)o * D + k);
    float4 r;
    r.x = g.x * w.x; r.y = g.y * w.y; r.z = g.z * w.z; r.w = g.w * w.w;
    *(float4*)(A + (size_t)m * D + k) = r;
}

// ---------------- backward step: Cout[m,j] = (opt) G[m/3, j] * sum_k Cin[m,k] * W[k,j]
// Cin [M3,256] row-major; W [256,NOUT] row-major (NN GEMM). Grid = (M3/BM)*(NOUT/BN).
template<int NOUT, bool SCALE>
__global__ __launch_bounds__(TB)
void bwd_kernel(const float* __restrict__ Cin, const float* __restrict__ W,
                const float* __restrict__ Gs, float* __restrict__ Cout)
{
    __shared__ float Ct[BK][BM + 4];   // transposed: Ct[k][m]
    __shared__ float Wt[BK][BN + 4];   // natural:    Wt[k][n]
    constexpr int NTILES = NOUT / BN;
    const int nt = blockIdx.x % NTILES;
    const int mt = blockIdx.x / NTILES;
    const int m0 = mt * BM, n0 = nt * BN;
    const int tid  = threadIdx.x;
    const int trow = (tid >> 4) << 2;
    const int tcol = (tid & 15) << 2;
    float acc[4][4] = {};

    for (int k0 = 0; k0 < D; k0 += BK) {
        #pragma unroll
        for (int t = 0; t < 2; ++t) {
            const int f4 = tid + t * TB;           // 0..511
            // Cin tile (transpose on write)
            const int row = f4 >> 3;               // 0..63
            const int c   = (f4 & 7) << 2;         // 0..28
            const float4 cv = *(const float4*)(Cin + (size_t)(m0 + row) * D + k0 + c);
            Ct[c + 0][row] = cv.x; Ct[c + 1][row] = cv.y;
            Ct[c + 2][row] = cv.z; Ct[c + 3][row] = cv.w;
            // W tile (natural orientation, direct float4 store)
            const int wrow = f4 >> 4;              // 0..31
            const int wc   = (f4 & 15) << 2;       // 0..60
            const float4 wv = *(const float4*)(W + (size_t)(k0 + wrow) * NOUT + n0 + wc);
            *(float4*)&Wt[wrow][wc] = wv;
        }
        __syncthreads();
        #pragma unroll
        for (int kk = 0; kk < BK; ++kk) {
            const float4 av = *(const float4*)&Ct[kk][trow];
            const float4 bv = *(const float4*)&Wt[kk][tcol];
            const float a[4] = {av.x, av.y, av.z, av.w};
            const float b[4] = {bv.x, bv.y, bv.z, bv.w};
            #pragma unroll
            for (int r = 0; r < 4; ++r)
                #pragma unroll
                for (int c = 0; c < 4; ++c)
                    acc[r][c] = fmaf(a[r], b[c], acc[r][c]);
        }
        __syncthreads();
    }

    #pragma unroll
    for (int r = 0; r < 4; ++r) {
        const int m = m0 + trow + r;
        float4 o;
        o.x = acc[r][0]; o.y = acc[r][1]; o.z = acc[r][2]; o.w = acc[r][3];
        if constexpr (SCALE) {
            const int b = m / 3;
            const float4 gv = *(const float4*)(Gs + (size_t)b * D + n0 + tcol);
            o.x *= gv.x; o.y *= gv.y; o.z *= gv.z; o.w *= gv.w;
        }
        *(float4*)(Cout + (size_t)m * NOUT + n0 + tcol) = o;
    }
}

extern "C" void kernel_launch(void* const* d_in, const int* in_sizes, int n_in,
                              void* d_out, int out_size, void* d_ws, size_t ws_size,
                              hipStream_t stream)
{
    const float* x  = (const float*)d_in[0];
    const float* W1 = (const float*)d_in[1];
    const float* b1 = (const float*)d_in[2];
    const float* W2 = (const float*)d_in[3];
    const float* b2 = (const float*)d_in[4];
    const float* W3 = (const float*)d_in[5];
    const float* b3 = (const float*)d_in[6];
    const float* W4 = (const float*)d_in[7];
    const float* b4 = (const float*)d_in[8];
    const float* W5 = (const float*)d_in[9];
    // b5 (d_in[10]) does not enter the Jacobian.

    // workspace layout (fp32): G1..G4, Ha, Hb  (each B*D), then Ca, Cb (each M3*D)
    // total = 6*2097152 + 2*6291456 floats = 100,663,296 bytes
    float* ws = (float*)d_ws;
    const size_t S  = (size_t)Bsz * D;
    const size_t S3 = (size_t)M3 * D;
    float* G1 = ws;
    float* G2 = G1 + S;
    float* G3 = G2 + S;
    float* G4 = G3 + S;
    float* Ha = G4 + S;
    float* Hb = Ha + S;
    float* Ca = Hb + S;
    float* Cb = Ca + S3;

    const int fwd_grid = (Bsz / BM) * (D / BN);   // 512
    fwd_kernel<64,  true ><<<fwd_grid, TB, 0, stream>>>(x,  W1, b1, G1, Ha);
    fwd_kernel<256, true ><<<fwd_grid, TB, 0, stream>>>(Ha, W2, b2, G2, Hb);
    fwd_kernel<256, true ><<<fwd_grid, TB, 0, stream>>>(Hb, W3, b3, G3, Ha);
    fwd_kernel<256, false><<<fwd_grid, TB, 0, stream>>>(Ha, W4, b4, G4, nullptr);

    expand_kernel<<<(M3 * (D / 4) + TB - 1) / TB, TB, 0, stream>>>(G4, W5, Ca);

    const int bwd_grid = (M3 / BM) * (D / BN);    // 1536
    bwd_kernel<256, true ><<<bwd_grid, TB, 0, stream>>>(Ca, W4, G3, Cb);
    bwd_kernel<256, true ><<<bwd_grid, TB, 0, stream>>>(Cb, W3, G2, Ca);
    bwd_kernel<256, true ><<<bwd_grid, TB, 0, stream>>>(Ca, W2, G1, Cb);
    bwd_kernel<64,  false><<<(M3 / BM), TB, 0, stream>>>(Cb, W1, nullptr, (float*)d_out);
}

// Round 2
// 144.770 us; speedup vs baseline: 1.6167x; 1.6167x over previous
//
#include <hip/hip_runtime.h>
#include <cstdint>
#include <cstddef>

// NetGrad J = W5 D4 W4 D3 W3 D2 W2 D1 W1, output [B,3,64].
// All GEMMs on MFMA f16 with hi/lo split operands (hi*hi + hi*lo + lo*hi):
// ~fp32 precision at 3x MFMA work, matrix pipe instead of vector ALU.

typedef _Float16 half_t;
typedef __attribute__((ext_vector_type(8))) _Float16 half8;
typedef __attribute__((ext_vector_type(4))) _Float16 half4;
typedef __attribute__((ext_vector_type(4))) float f32x4;

constexpr int Bsz = 8192;
constexpr int D   = 256;
constexpr int M3  = Bsz * 3;

// ---------- split fp32 -> f16 hi/lo (elementwise, 4-wide) ----------
__global__ __launch_bounds__(256)
void split_f32(const float* __restrict__ src, half_t* __restrict__ hi,
               half_t* __restrict__ lo, int n4)
{
    const int i = blockIdx.x * 256 + threadIdx.x;
    if (i >= n4) return;
    const float4 v = ((const float4*)src)[i];
    half4 h, l;
    h[0] = (half_t)v.x; l[0] = (half_t)(v.x - (float)h[0]);
    h[1] = (half_t)v.y; l[1] = (half_t)(v.y - (float)h[1]);
    h[2] = (half_t)v.z; l[2] = (half_t)(v.z - (float)h[2]);
    h[3] = (half_t)v.w; l[3] = (half_t)(v.w - (float)h[3]);
    ((half4*)hi)[i] = h;
    ((half4*)lo)[i] = l;
}

// ---------- transpose + split: src[R][C] fp32 -> thi/tlo[C][R] f16 ----------
__global__ __launch_bounds__(256)
void tsplit(const float* __restrict__ src, half_t* __restrict__ thi,
            half_t* __restrict__ tlo, int R, int C)
{
    __shared__ float tile[32][33];
    const int tx = threadIdx.x & 31, ty = threadIdx.x >> 5;
    const int bx = blockIdx.x, by = blockIdx.y;
    #pragma unroll
    for (int i = 0; i < 32; i += 8)
        tile[ty + i][tx] = src[(size_t)(by * 32 + ty + i) * C + bx * 32 + tx];
    __syncthreads();
    #pragma unroll
    for (int i = 0; i < 32; i += 8) {
        const float v = tile[tx][ty + i];
        const size_t o = (size_t)(bx * 32 + ty + i) * R + by * 32 + tx;
        const half_t h = (half_t)v;
        thi[o] = h;
        tlo[o] = (half_t)(v - (float)h);
    }
}

// ---------- expand: C0[b*3+o, k] = W5[o,k]*G4[b,k], written as hi/lo f16 ----------
__global__ __launch_bounds__(256)
void expand_split(const float* __restrict__ G4, const float* __restrict__ W5,
                  half_t* __restrict__ Ch, half_t* __restrict__ Cl)
{
    const int idx = blockIdx.x * 256 + threadIdx.x;   // over M3*64 quads
    const int m = idx >> 6;
    const int k = (idx & 63) << 2;
    const int b = m / 3;
    const int o = m - b * 3;
    const float4 g = *(const float4*)(G4 + (size_t)b * D + k);
    const float4 w = *(const float4*)(W5 + (size_t)o * D + k);
    const float v0 = g.x * w.x, v1 = g.y * w.y, v2 = g.z * w.z, v3 = g.w * w.w;
    half4 h, l;
    h[0] = (half_t)v0; l[0] = (half_t)(v0 - (float)h[0]);
    h[1] = (half_t)v1; l[1] = (half_t)(v1 - (float)h[1]);
    h[2] = (half_t)v2; l[2] = (half_t)(v2 - (float)h[2]);
    h[3] = (half_t)v3; l[3] = (half_t)(v3 - (float)h[3]);
    *(half4*)(Ch + (size_t)m * D + k) = h;
    *(half4*)(Cl + (size_t)m * D + k) = l;
}

// ---------- fwd MFMA layer: Pre = H @ W^T + b; G = elu'(Pre); H' = elu(Pre) ----------
// A = H split [M,K]; B(LDS) rows = W rows [j][k] (storage orientation, no transpose).
// BM=64, BN=64, 4 waves 2x2, wave tile 32x32, 16x16x32 f16 MFMA.
template<int K, bool WRITE_H>
__global__ __launch_bounds__(256)
void fwd_mfma(const half_t* __restrict__ Ah, const half_t* __restrict__ Al,
              const half_t* __restrict__ Wh, const half_t* __restrict__ Wl,
              const float* __restrict__ bias, float* __restrict__ G,
              half_t* __restrict__ Hh, half_t* __restrict__ Hl)
{
    constexpr int FM = 2, FN = 2;
    __shared__ half_t As[2][64 * 40];
    __shared__ half_t Bs[2][64 * 40];
    const int tid = threadIdx.x;
    const int nt = blockIdx.x & 3, mt = blockIdx.x >> 2;
    const int m0 = mt * 64, n0 = nt * 64;
    const int wave = tid >> 6, lane = tid & 63;
    const int wm = wave >> 1, wn = wave & 1;
    const int lrow = lane & 15, kgrp = lane >> 4;
    const int srow = tid >> 2, sseg = tid & 3;
    f32x4 acc[FM][FN] = {};

    for (int k0 = 0; k0 < K; k0 += 32) {
        {
            const size_t ga = (size_t)(m0 + srow) * K + k0 + sseg * 8;
            *(half8*)&As[0][srow * 40 + sseg * 8] = *(const half8*)(Ah + ga);
            *(half8*)&As[1][srow * 40 + sseg * 8] = *(const half8*)(Al + ga);
            const size_t gb = (size_t)(n0 + srow) * K + k0 + sseg * 8;
            *(half8*)&Bs[0][srow * 40 + sseg * 8] = *(const half8*)(Wh + gb);
            *(half8*)&Bs[1][srow * 40 + sseg * 8] = *(const half8*)(Wl + gb);
        }
        __syncthreads();
        half8 a[2][FM], b[2][FN];
        #pragma unroll
        for (int fm = 0; fm < FM; ++fm) {
            const int off = (wm * 32 + fm * 16 + lrow) * 40 + kgrp * 8;
            a[0][fm] = *(const half8*)&As[0][off];
            a[1][fm] = *(const half8*)&As[1][off];
        }
        #pragma unroll
        for (int fn = 0; fn < FN; ++fn) {
            const int off = (wn * 32 + fn * 16 + lrow) * 40 + kgrp * 8;
            b[0][fn] = *(const half8*)&Bs[0][off];
            b[1][fn] = *(const half8*)&Bs[1][off];
        }
        #pragma unroll
        for (int fm = 0; fm < FM; ++fm)
            #pragma unroll
            for (int fn = 0; fn < FN; ++fn) {
                acc[fm][fn] = __builtin_amdgcn_mfma_f32_16x16x32_f16(a[0][fm], b[0][fn], acc[fm][fn], 0, 0, 0);
                acc[fm][fn] = __builtin_amdgcn_mfma_f32_16x16x32_f16(a[0][fm], b[1][fn], acc[fm][fn], 0, 0, 0);
                acc[fm][fn] = __builtin_amdgcn_mfma_f32_16x16x32_f16(a[1][fm], b[0][fn], acc[fm][fn], 0, 0, 0);
            }
        __syncthreads();
    }

    #pragma unroll
    for (int fn = 0; fn < FN; ++fn) {
        const int col = n0 + wn * 32 + fn * 16 + lrow;
        const float bc = bias[col];
        #pragma unroll
        for (int fm = 0; fm < FM; ++fm) {
            const int rbase = m0 + wm * 32 + fm * 16 + kgrp * 4;
            #pragma unroll
            for (int r = 0; r < 4; ++r) {
                const int row = rbase + r;
                const float pre = acc[fm][fn][r] + bc;
                float g, h;
                if (pre > 0.f) { g = 1.f; h = pre; }
                else           { g = __expf(pre); h = g - 1.f; }
                G[(size_t)row * D + col] = g;
                if constexpr (WRITE_H) {
                    const half_t hh = (half_t)h;
                    Hh[(size_t)row * D + col] = hh;
                    Hl[(size_t)row * D + col] = (half_t)(h - (float)hh);
                }
            }
        }
    }
}

// ---------- bwd MFMA step: Cout[m,j] = (G[m/3,j]) * sum_k Cin[m,k] * WT[j,k] ----------
// WT is pre-transposed W (WT[j][k] = W[k][j]) split hi/lo. BM=64; BN_=128 (mid) or 64 (final).
template<int BN_, int NOUT, bool SCALE, bool FINAL>
__global__ __launch_bounds__(256)
void bwd_mfma(const half_t* __restrict__ Ah, const half_t* __restrict__ Al,
              const half_t* __restrict__ Bh_, const half_t* __restrict__ Bl_,
              const float* __restrict__ Gs, half_t* __restrict__ Coh,
              half_t* __restrict__ Col, float* __restrict__ out)
{
    constexpr int SPAN = BN_ / 2, FN = SPAN / 16, FM = 2, NT = NOUT / BN_;
    __shared__ half_t As[2][64 * 40];
    __shared__ half_t Bs[2][BN_ * 40];
    const int tid = threadIdx.x;
    const int nt = (NT == 1) ? 0 : (int)(blockIdx.x & (NT - 1));
    const int mt = (NT == 1) ? (int)blockIdx.x : (int)(blockIdx.x >> 1);
    const int m0 = mt * 64, n0 = nt * BN_;
    const int wave = tid >> 6, lane = tid & 63;
    const int wm = wave >> 1, wn = wave & 1;
    const int lrow = lane & 15, kgrp = lane >> 4;
    const int srow = tid >> 2, sseg = tid & 3;
    f32x4 acc[FM][FN] = {};

    for (int k0 = 0; k0 < 256; k0 += 32) {
        {
            const size_t ga = (size_t)(m0 + srow) * 256 + k0 + sseg * 8;
            *(half8*)&As[0][srow * 40 + sseg * 8] = *(const half8*)(Ah + ga);
            *(half8*)&As[1][srow * 40 + sseg * 8] = *(const half8*)(Al + ga);
            #pragma unroll
            for (int rr = 0; rr < BN_; rr += 64) {
                const int row = srow + rr;
                const size_t gb = (size_t)(n0 + row) * 256 + k0 + sseg * 8;
                *(half8*)&Bs[0][row * 40 + sseg * 8] = *(const half8*)(Bh_ + gb);
                *(half8*)&Bs[1][row * 40 + sseg * 8] = *(const half8*)(Bl_ + gb);
            }
        }
        __syncthreads();
        half8 a[2][FM], b[2][FN];
        #pragma unroll
        for (int fm = 0; fm < FM; ++fm) {
            const int off = (wm * 32 + fm * 16 + lrow) * 40 + kgrp * 8;
            a[0][fm] = *(const half8*)&As[0][off];
            a[1][fm] = *(const half8*)&As[1][off];
        }
        #pragma unroll
        for (int fn = 0; fn < FN; ++fn) {
            const int off = (wn * SPAN + fn * 16 + lrow) * 40 + kgrp * 8;
            b[0][fn] = *(const half8*)&Bs[0][off];
            b[1][fn] = *(const half8*)&Bs[1][off];
        }
        #pragma unroll
        for (int fm = 0; fm < FM; ++fm)
            #pragma unroll
            for (int fn = 0; fn < FN; ++fn) {
                acc[fm][fn] = __builtin_amdgcn_mfma_f32_16x16x32_f16(a[0][fm], b[0][fn], acc[fm][fn], 0, 0, 0);
                acc[fm][fn] = __builtin_amdgcn_mfma_f32_16x16x32_f16(a[0][fm], b[1][fn], acc[fm][fn], 0, 0, 0);
                acc[fm][fn] = __builtin_amdgcn_mfma_f32_16x16x32_f16(a[1][fm], b[0][fn], acc[fm][fn], 0, 0, 0);
            }
        __syncthreads();
    }

    #pragma unroll
    for (int fn = 0; fn < FN; ++fn) {
        const int col = n0 + wn * SPAN + fn * 16 + lrow;
        #pragma unroll
        for (int fm = 0; fm < FM; ++fm) {
            const int rbase = m0 + wm * 32 + fm * 16 + kgrp * 4;
            #pragma unroll
            for (int r = 0; r < 4; ++r) {
                const int row = rbase + r;
                float v = acc[fm][fn][r];
                if constexpr (SCALE)
                    v *= Gs[(size_t)(row / 3) * D + col];
                if constexpr (FINAL) {
                    out[(size_t)row * NOUT + col] = v;
                } else {
                    const half_t h = (half_t)v;
                    Coh[(size_t)row * D + col] = h;
                    Col[(size_t)row * D + col] = (half_t)(v - (float)h);
                }
            }
        }
    }
}

extern "C" void kernel_launch(void* const* d_in, const int* in_sizes, int n_in,
                              void* d_out, int out_size, void* d_ws, size_t ws_size,
                              hipStream_t stream)
{
    const float* x  = (const float*)d_in[0];
    const float* W1 = (const float*)d_in[1];
    const float* b1 = (const float*)d_in[2];
    const float* W2 = (const float*)d_in[3];
    const float* b2 = (const float*)d_in[4];
    const float* W3 = (const float*)d_in[5];
    const float* b3 = (const float*)d_in[6];
    const float* W4 = (const float*)d_in[7];
    const float* b4 = (const float*)d_in[8];
    const float* W5 = (const float*)d_in[9];

    // ---- workspace carve (87.7 MB; fwd H buffers alias bwd C buffers) ----
    char* p = (char*)d_ws;
    float* G1 = (float*)p; p += (size_t)Bsz * D * 4;
    float* G2 = (float*)p; p += (size_t)Bsz * D * 4;
    float* G3 = (float*)p; p += (size_t)Bsz * D * 4;
    float* G4 = (float*)p; p += (size_t)Bsz * D * 4;
    half_t* CAh = (half_t*)p; p += (size_t)M3 * D * 2;
    half_t* CAl = (half_t*)p; p += (size_t)M3 * D * 2;
    half_t* CBh = (half_t*)p; p += (size_t)M3 * D * 2;
    half_t* CBl = (half_t*)p; p += (size_t)M3 * D * 2;
    // H ping/pong aliases (each needs only 4 MB of the 12.6 MB C regions;
    // H dead before expand/bwd writes C — stream-ordered, safe)
    half_t* HAh = CAh; half_t* HAl = CAl;
    half_t* HBh = CBh; half_t* HBl = CBl;
    half_t* Xh = (half_t*)p; p += (size_t)Bsz * 64 * 2;
    half_t* Xl = (half_t*)p; p += (size_t)Bsz * 64 * 2;
    half_t* W1fh = (half_t*)p; p += 256 * 64 * 2;
    half_t* W1fl = (half_t*)p; p += 256 * 64 * 2;
    half_t* W2fh = (half_t*)p; p += 256 * 256 * 2;
    half_t* W2fl = (half_t*)p; p += 256 * 256 * 2;
    half_t* W3fh = (half_t*)p; p += 256 * 256 * 2;
    half_t* W3fl = (half_t*)p; p += 256 * 256 * 2;
    half_t* W4fh = (half_t*)p; p += 256 * 256 * 2;
    half_t* W4fl = (half_t*)p; p += 256 * 256 * 2;
    half_t* T1h = (half_t*)p; p += 64 * 256 * 2;   // WT1[j=64][k=256]
    half_t* T1l = (half_t*)p; p += 64 * 256 * 2;
    half_t* T2h = (half_t*)p; p += 256 * 256 * 2;
    half_t* T2l = (half_t*)p; p += 256 * 256 * 2;
    half_t* T3h = (half_t*)p; p += 256 * 256 * 2;
    half_t* T3l = (half_t*)p; p += 256 * 256 * 2;
    half_t* T4h = (half_t*)p; p += 256 * 256 * 2;
    half_t* T4l = (half_t*)p; p += 256 * 256 * 2;

    // ---- prep: splits ----
    split_f32<<<512, 256, 0, stream>>>(x,  Xh,   Xl,   Bsz * 64 / 4);
    split_f32<<<16,  256, 0, stream>>>(W1, W1fh, W1fl, 256 * 64 / 4);
    split_f32<<<64,  256, 0, stream>>>(W2, W2fh, W2fl, 256 * 256 / 4);
    split_f32<<<64,  256, 0, stream>>>(W3, W3fh, W3fl, 256 * 256 / 4);
    split_f32<<<64,  256, 0, stream>>>(W4, W4fh, W4fl, 256 * 256 / 4);
    tsplit<<<dim3(2, 8), 256, 0, stream>>>(W1, T1h, T1l, 256, 64);    // [256,64] -> [64,256]
    tsplit<<<dim3(8, 8), 256, 0, stream>>>(W2, T2h, T2l, 256, 256);
    tsplit<<<dim3(8, 8), 256, 0, stream>>>(W3, T3h, T3l, 256, 256);
    tsplit<<<dim3(8, 8), 256, 0, stream>>>(W4, T4h, T4l, 256, 256);

    // ---- forward: G_i and split H ----
    fwd_mfma<64,  true ><<<512, 256, 0, stream>>>(Xh,  Xl,  W1fh, W1fl, b1, G1, HAh, HAl);
    fwd_mfma<256, true ><<<512, 256, 0, stream>>>(HAh, HAl, W2fh, W2fl, b2, G2, HBh, HBl);
    fwd_mfma<256, true ><<<512, 256, 0, stream>>>(HBh, HBl, W3fh, W3fl, b3, G3, HAh, HAl);
    fwd_mfma<256, false><<<512, 256, 0, stream>>>(HAh, HAl, W4fh, W4fl, b4, G4, nullptr, nullptr);

    // ---- backward chain (3 output rows per sample, flattened M3) ----
    expand_split<<<M3 * 64 / 256, 256, 0, stream>>>(G4, W5, CAh, CAl);
    bwd_mfma<128, 256, true,  false><<<768, 256, 0, stream>>>(CAh, CAl, T4h, T4l, G3, CBh, CBl, nullptr);
    bwd_mfma<128, 256, true,  false><<<768, 256, 0, stream>>>(CBh, CBl, T3h, T3l, G2, CAh, CAl, nullptr);
    bwd_mfma<128, 256, true,  false><<<768, 256, 0, stream>>>(CAh, CAl, T2h, T2l, G1, CBh, CBl, nullptr);
    bwd_mfma<64,  64,  false, true ><<<384, 256, 0, stream>>>(CBh, CBl, T1h, T1l, nullptr, nullptr, nullptr, (float*)d_out);
}

// Round 3
// 131.490 us; speedup vs baseline: 1.7800x; 1.1010x over previous
//
#include <hip/hip_runtime.h>
#include <cstdint>
#include <cstddef>

// NetGrad J = W5 D4 W4 D3 W3 D2 W2 D1 W1, output [B,3,64].
// Fully fused: prep (W split/transpose) + fwd (per-16-sample H chain in LDS,
// writes G1..G4) + bwd (per-16-sample 48-row C chain in LDS, writes J).
// GEMMs: MFMA f16 hi/lo split (hi*hi + hi*lo + lo*hi), fp32 accumulate.
// B-operand fragments read straight from global (W ~1MB, L2-resident).

typedef _Float16 half_t;
typedef __attribute__((ext_vector_type(8))) _Float16 half8;
typedef __attribute__((ext_vector_type(4))) float f32x4;

constexpr int Bsz = 8192;
constexpr int D   = 256;
constexpr int M3  = Bsz * 3;
constexpr int LDA = 264;          // LDS row stride in halves (528 B -> 2-way max)

// ---------------- prep: split (native) + transpose-split all weights ----------------
// W1 [256,64] -> W1h/l [256,64], T1h/l [64,256]
// W2..W4 [256,256] -> Wkh/l native, Tkh/l transposed
__global__ __launch_bounds__(256)
void prep_split(const float* __restrict__ W1, const float* __restrict__ W2,
                const float* __restrict__ W3, const float* __restrict__ W4,
                half_t* W1h, half_t* W1l, half_t* T1h, half_t* T1l,
                half_t* W2h, half_t* W2l, half_t* T2h, half_t* T2l,
                half_t* W3h, half_t* W3l, half_t* T3h, half_t* T3l,
                half_t* W4h, half_t* W4l, half_t* T4h, half_t* T4l)
{
    __shared__ float tile[32][33];
    const int bid = blockIdx.x;
    const float* src; half_t *sh, *sl, *th, *tl; int C, bx, by;
    if (bid < 16) {
        src = W1; sh = W1h; sl = W1l; th = T1h; tl = T1l;
        C = 64; bx = bid & 1; by = bid >> 1;
    } else {
        const int q = bid - 16, j = q >> 6, lo = q & 63;
        bx = lo & 7; by = lo >> 3; C = 256;
        if (j == 0)      { src = W2; sh = W2h; sl = W2l; th = T2h; tl = T2l; }
        else if (j == 1) { src = W3; sh = W3h; sl = W3l; th = T3h; tl = T3l; }
        else             { src = W4; sh = W4h; sl = W4l; th = T4h; tl = T4l; }
    }
    const int R = 256;
    const int tx = threadIdx.x & 31, ty = threadIdx.x >> 5;
    #pragma unroll
    for (int i = 0; i < 32; i += 8) {
        const size_t o = (size_t)(by * 32 + ty + i) * C + bx * 32 + tx;
        const float v = src[o];
        tile[ty + i][tx] = v;
        const half_t h = (half_t)v;
        sh[o] = h; sl[o] = (half_t)(v - (float)h);
    }
    __syncthreads();
    #pragma unroll
    for (int i = 0; i < 32; i += 8) {
        const float v = tile[tx][ty + i];
        const half_t h = (half_t)v;
        const size_t o = (size_t)(bx * 32 + ty + i) * R + by * 32 + tx;
        th[o] = h; tl[o] = (half_t)(v - (float)h);
    }
}

// ---------------- fused forward ----------------
// Block = 16 samples. A (H hi/lo) lives in LDS [16][LDA]. Per layer:
// pre = H @ W^T + b (MFMA, B-frags from global native-layout split W),
// G -> global fp32, H' = elu(pre) -> back into LDS.
__device__ __forceinline__
void fwd_layer(half_t* __restrict__ Ah, half_t* __restrict__ Al,
               const half_t* __restrict__ Wh, const half_t* __restrict__ Wl,
               const float* __restrict__ bias, float* __restrict__ G,
               int K, bool writeH, int m0, int n0w, int lrow, int kgrp)
{
    f32x4 acc[4] = {};
    for (int k0 = 0; k0 < K; k0 += 32) {
        const int ko = k0 + kgrp * 8;
        const half8 ah = *(const half8*)&Ah[lrow * LDA + ko];
        const half8 al = *(const half8*)&Al[lrow * LDA + ko];
        #pragma unroll
        for (int fn = 0; fn < 4; ++fn) {
            const int col = n0w + fn * 16 + lrow;
            const half8 bh = *(const half8*)(Wh + (size_t)col * K + ko);
            const half8 bl = *(const half8*)(Wl + (size_t)col * K + ko);
            acc[fn] = __builtin_amdgcn_mfma_f32_16x16x32_f16(ah, bh, acc[fn], 0, 0, 0);
            acc[fn] = __builtin_amdgcn_mfma_f32_16x16x32_f16(ah, bl, acc[fn], 0, 0, 0);
            acc[fn] = __builtin_amdgcn_mfma_f32_16x16x32_f16(al, bh, acc[fn], 0, 0, 0);
        }
    }
    __syncthreads();                      // all reads of A done before overwrite
    #pragma unroll
    for (int fn = 0; fn < 4; ++fn) {
        const int col = n0w + fn * 16 + lrow;
        const float bc = bias[col];
        #pragma unroll
        for (int r = 0; r < 4; ++r) {
            const int row = kgrp * 4 + r;
            const float pre = acc[fn][r] + bc;
            float g, h;
            if (pre > 0.f) { g = 1.f; h = pre; }
            else           { g = __expf(pre); h = g - 1.f; }
            G[(size_t)(m0 + row) * D + col] = g;
            if (writeH) {
                const half_t hh = (half_t)h;
                Ah[row * LDA + col] = hh;
                Al[row * LDA + col] = (half_t)(h - (float)hh);
            }
        }
    }
    __syncthreads();
}

__global__ __launch_bounds__(256)
void fwd_fused(const float* __restrict__ x,
               const half_t* __restrict__ W1h, const half_t* __restrict__ W1l, const float* __restrict__ b1, float* __restrict__ G1,
               const half_t* __restrict__ W2h, const half_t* __restrict__ W2l, const float* __restrict__ b2, float* __restrict__ G2,
               const half_t* __restrict__ W3h, const half_t* __restrict__ W3l, const float* __restrict__ b3, float* __restrict__ G3,
               const half_t* __restrict__ W4h, const half_t* __restrict__ W4l, const float* __restrict__ b4, float* __restrict__ G4)
{
    __shared__ half_t Ah[16 * LDA];
    __shared__ half_t Al[16 * LDA];
    const int tid = threadIdx.x;
    const int m0 = blockIdx.x * 16;
    {   // load + split x [16][64]
        const int row = tid >> 4, c4 = (tid & 15) * 4;
        const float4 v = *(const float4*)(x + (size_t)(m0 + row) * 64 + c4);
        const float vv[4] = {v.x, v.y, v.z, v.w};
        #pragma unroll
        for (int j = 0; j < 4; ++j) {
            const half_t h = (half_t)vv[j];
            Ah[row * LDA + c4 + j] = h;
            Al[row * LDA + c4 + j] = (half_t)(vv[j] - (float)h);
        }
    }
    __syncthreads();
    const int lane = tid & 63, lrow = lane & 15, kgrp = lane >> 4;
    const int n0w = (tid >> 6) * 64;
    fwd_layer(Ah, Al, W1h, W1l, b1, G1,  64, true,  m0, n0w, lrow, kgrp);
    fwd_layer(Ah, Al, W2h, W2l, b2, G2, 256, true,  m0, n0w, lrow, kgrp);
    fwd_layer(Ah, Al, W3h, W3l, b3, G3, 256, true,  m0, n0w, lrow, kgrp);
    fwd_layer(Ah, Al, W4h, W4l, b4, G4, 256, false, m0, n0w, lrow, kgrp);
}

// ---------------- fused backward ----------------
// Block = 16 samples = 48 chain rows. C hi/lo lives in LDS [48][LDA].
// expand: C0 = (W5 * G4-row)  -> 3 mid steps C = (C @ T) * G  -> final C @ T1 -> out.
__device__ __forceinline__
void bwd_mid(half_t* __restrict__ Ch, half_t* __restrict__ Cl,
             const half_t* __restrict__ Th, const half_t* __restrict__ Tl,
             const float* __restrict__ Gsc, int m0s, int n0w, int lrow, int kgrp)
{
    f32x4 acc[3][4] = {};
    for (int k0 = 0; k0 < 256; k0 += 32) {
        const int ko = k0 + kgrp * 8;
        half8 ah[3], al[3];
        #pragma unroll
        for (int fm = 0; fm < 3; ++fm) {
            ah[fm] = *(const half8*)&Ch[(fm * 16 + lrow) * LDA + ko];
            al[fm] = *(const half8*)&Cl[(fm * 16 + lrow) * LDA + ko];
        }
        #pragma unroll
        for (int fn = 0; fn < 4; ++fn) {
            const int col = n0w + fn * 16 + lrow;
            const half8 bh = *(const half8*)(Th + (size_t)col * 256 + ko);
            const half8 bl = *(const half8*)(Tl + (size_t)col * 256 + ko);
            #pragma unroll
            for (int fm = 0; fm < 3; ++fm) {
                acc[fm][fn] = __builtin_amdgcn_mfma_f32_16x16x32_f16(ah[fm], bh, acc[fm][fn], 0, 0, 0);
                acc[fm][fn] = __builtin_amdgcn_mfma_f32_16x16x32_f16(ah[fm], bl, acc[fm][fn], 0, 0, 0);
                acc[fm][fn] = __builtin_amdgcn_mfma_f32_16x16x32_f16(al[fm], bh, acc[fm][fn], 0, 0, 0);
            }
        }
    }
    __syncthreads();
    #pragma unroll
    for (int fn = 0; fn < 4; ++fn) {
        const int col = n0w + fn * 16 + lrow;
        #pragma unroll
        for (int fm = 0; fm < 3; ++fm) {
            #pragma unroll
            for (int r = 0; r < 4; ++r) {
                const int row = fm * 16 + kgrp * 4 + r;
                const float g = Gsc[(size_t)(m0s + row / 3) * D + col];
                const float v = acc[fm][fn][r] * g;
                const half_t h = (half_t)v;
                Ch[row * LDA + col] = h;
                Cl[row * LDA + col] = (half_t)(v - (float)h);
            }
        }
    }
    __syncthreads();
}

__global__ __launch_bounds__(256)
void bwd_fused(const float* __restrict__ G4, const float* __restrict__ W5,
               const half_t* __restrict__ T4h, const half_t* __restrict__ T4l, const float* __restrict__ G3,
               const half_t* __restrict__ T3h, const half_t* __restrict__ T3l, const float* __restrict__ G2,
               const half_t* __restrict__ T2h, const half_t* __restrict__ T2l, const float* __restrict__ G1,
               const half_t* __restrict__ T1h, const half_t* __restrict__ T1l,
               float* __restrict__ out)
{
    __shared__ half_t Ch[48 * LDA];
    __shared__ half_t Cl[48 * LDA];
    const int tid = threadIdx.x;
    const int m0s = blockIdx.x * 16;        // sample base
    const int mr0 = blockIdx.x * 48;        // chain-row base

    // expand: C0[r][k] = W5[r%3][k] * G4[m0s + r/3][k]
    #pragma unroll
    for (int t = 0; t < 12; ++t) {
        const int idx = tid + t * 256;       // 0..3071 float4s
        const int r = idx >> 6;
        const int k4 = (idx & 63) * 4;
        const int b = m0s + r / 3, o = r - (r / 3) * 3;
        const float4 g = *(const float4*)(G4 + (size_t)b * D + k4);
        const float4 w = *(const float4*)(W5 + (size_t)o * D + k4);
        const float vv[4] = {g.x * w.x, g.y * w.y, g.z * w.z, g.w * w.w};
        #pragma unroll
        for (int j = 0; j < 4; ++j) {
            const half_t h = (half_t)vv[j];
            Ch[r * LDA + k4 + j] = h;
            Cl[r * LDA + k4 + j] = (half_t)(vv[j] - (float)h);
        }
    }
    __syncthreads();

    const int lane = tid & 63, lrow = lane & 15, kgrp = lane >> 4;
    const int wave = tid >> 6;
    const int n0w = wave * 64;

    bwd_mid(Ch, Cl, T4h, T4l, G3, m0s, n0w, lrow, kgrp);
    bwd_mid(Ch, Cl, T3h, T3l, G2, m0s, n0w, lrow, kgrp);
    bwd_mid(Ch, Cl, T2h, T2l, G1, m0s, n0w, lrow, kgrp);

    // final: [48][256] @ T1[64][256]^T -> out [48][64]
    {
        const int n0f = wave * 16;
        f32x4 acc[3] = {};
        for (int k0 = 0; k0 < 256; k0 += 32) {
            const int ko = k0 + kgrp * 8;
            const int col = n0f + lrow;
            const half8 bh = *(const half8*)(T1h + (size_t)col * 256 + ko);
            const half8 bl = *(const half8*)(T1l + (size_t)col * 256 + ko);
            #pragma unroll
            for (int fm = 0; fm < 3; ++fm) {
                const half8 ah = *(const half8*)&Ch[(fm * 16 + lrow) * LDA + ko];
                const half8 al = *(const half8*)&Cl[(fm * 16 + lrow) * LDA + ko];
                acc[fm] = __builtin_amdgcn_mfma_f32_16x16x32_f16(ah, bh, acc[fm], 0, 0, 0);
                acc[fm] = __builtin_amdgcn_mfma_f32_16x16x32_f16(ah, bl, acc[fm], 0, 0, 0);
                acc[fm] = __builtin_amdgcn_mfma_f32_16x16x32_f16(al, bh, acc[fm], 0, 0, 0);
            }
        }
        const int col = n0f + lrow;
        #pragma unroll
        for (int fm = 0; fm < 3; ++fm)
            #pragma unroll
            for (int r = 0; r < 4; ++r) {
                const int row = fm * 16 + kgrp * 4 + r;
                out[(size_t)(mr0 + row) * 64 + col] = acc[fm][r];
            }
    }
}

extern "C" void kernel_launch(void* const* d_in, const int* in_sizes, int n_in,
                              void* d_out, int out_size, void* d_ws, size_t ws_size,
                              hipStream_t stream)
{
    const float* x  = (const float*)d_in[0];
    const float* W1 = (const float*)d_in[1];
    const float* b1 = (const float*)d_in[2];
    const float* W2 = (const float*)d_in[3];
    const float* b2 = (const float*)d_in[4];
    const float* W3 = (const float*)d_in[5];
    const float* b3 = (const float*)d_in[6];
    const float* W4 = (const float*)d_in[7];
    const float* b4 = (const float*)d_in[8];
    const float* W5 = (const float*)d_in[9];

    // ---- workspace carve (~34 MB) ----
    char* p = (char*)d_ws;
    float* G1 = (float*)p; p += (size_t)Bsz * D * 4;
    float* G2 = (float*)p; p += (size_t)Bsz * D * 4;
    float* G3 = (float*)p; p += (size_t)Bsz * D * 4;
    float* G4 = (float*)p; p += (size_t)Bsz * D * 4;
    half_t* W1h = (half_t*)p; p += 256 * 64 * 2;
    half_t* W1l = (half_t*)p; p += 256 * 64 * 2;
    half_t* T1h = (half_t*)p; p += 64 * 256 * 2;
    half_t* T1l = (half_t*)p; p += 64 * 256 * 2;
    half_t* W2h = (half_t*)p; p += 256 * 256 * 2;
    half_t* W2l = (half_t*)p; p += 256 * 256 * 2;
    half_t* T2h = (half_t*)p; p += 256 * 256 * 2;
    half_t* T2l = (half_t*)p; p += 256 * 256 * 2;
    half_t* W3h = (half_t*)p; p += 256 * 256 * 2;
    half_t* W3l = (half_t*)p; p += 256 * 256 * 2;
    half_t* T3h = (half_t*)p; p += 256 * 256 * 2;
    half_t* T3l = (half_t*)p; p += 256 * 256 * 2;
    half_t* W4h = (half_t*)p; p += 256 * 256 * 2;
    half_t* W4l = (half_t*)p; p += 256 * 256 * 2;
    half_t* T4h = (half_t*)p; p += 256 * 256 * 2;
    half_t* T4l = (half_t*)p; p += 256 * 256 * 2;

    prep_split<<<208, 256, 0, stream>>>(W1, W2, W3, W4,
        W1h, W1l, T1h, T1l, W2h, W2l, T2h, T2l,
        W3h, W3l, T3h, T3l, W4h, W4l, T4h, T4l);

    fwd_fused<<<Bsz / 16, 256, 0, stream>>>(x,
        W1h, W1l, b1, G1,  W2h, W2l, b2, G2,
        W3h, W3l, b3, G3,  W4h, W4l, b4, G4);

    bwd_fused<<<Bsz / 16, 256, 0, stream>>>(G4, W5,
        T4h, T4l, G3,  T3h, T3l, G2,  T2h, T2l, G1,
        T1h, T1l, (float*)d_out);
}

// Round 4
// 115.742 us; speedup vs baseline: 2.0222x; 1.1361x over previous
//
#include <hip/hip_runtime.h>
#include <cstdint>
#include <cstddef>

// NetGrad J = W5 D4 W4 D3 W3 D2 W2 D1 W1, output [B,3,64].
// Fused: prep (W split/transpose) + fwd (16-sample H chain in LDS, writes G1..G4)
// + bwd (16-sample 48-row C chain in LDS, row layout o*16+s, writes J).
// GEMMs: MFMA f16 hi/lo split (hi*hi + hi*lo + lo*hi), fp32 accumulate.
// 512-thread blocks (8 waves, 32-col span each) for latency hiding.

typedef _Float16 half_t;
typedef __attribute__((ext_vector_type(8))) _Float16 half8;
typedef __attribute__((ext_vector_type(4))) float f32x4;

constexpr int Bsz = 8192;
constexpr int D   = 256;
constexpr int LDA = 264;          // LDS row stride in halves (528 B)

// ---------------- prep: split (native) + transpose-split all weights ----------------
__global__ __launch_bounds__(256)
void prep_split(const float* __restrict__ W1, const float* __restrict__ W2,
                const float* __restrict__ W3, const float* __restrict__ W4,
                half_t* W1h, half_t* W1l, half_t* T1h, half_t* T1l,
                half_t* W2h, half_t* W2l, half_t* T2h, half_t* T2l,
                half_t* W3h, half_t* W3l, half_t* T3h, half_t* T3l,
                half_t* W4h, half_t* W4l, half_t* T4h, half_t* T4l)
{
    __shared__ float tile[32][33];
    const int bid = blockIdx.x;
    const float* src; half_t *sh, *sl, *th, *tl; int C, bx, by;
    if (bid < 16) {
        src = W1; sh = W1h; sl = W1l; th = T1h; tl = T1l;
        C = 64; bx = bid & 1; by = bid >> 1;
    } else {
        const int q = bid - 16, j = q >> 6, lo = q & 63;
        bx = lo & 7; by = lo >> 3; C = 256;
        if (j == 0)      { src = W2; sh = W2h; sl = W2l; th = T2h; tl = T2l; }
        else if (j == 1) { src = W3; sh = W3h; sl = W3l; th = T3h; tl = T3l; }
        else             { src = W4; sh = W4h; sl = W4l; th = T4h; tl = T4l; }
    }
    const int R = 256;
    const int tx = threadIdx.x & 31, ty = threadIdx.x >> 5;
    #pragma unroll
    for (int i = 0; i < 32; i += 8) {
        const size_t o = (size_t)(by * 32 + ty + i) * C + bx * 32 + tx;
        const float v = src[o];
        tile[ty + i][tx] = v;
        const half_t h = (half_t)v;
        sh[o] = h; sl[o] = (half_t)(v - (float)h);
    }
    __syncthreads();
    #pragma unroll
    for (int i = 0; i < 32; i += 8) {
        const float v = tile[tx][ty + i];
        const half_t h = (half_t)v;
        const size_t o = (size_t)(bx * 32 + ty + i) * R + by * 32 + tx;
        th[o] = h; tl[o] = (half_t)(v - (float)h);
    }
}

// ---------------- fused forward ----------------
// Block = 16 samples, 512 threads (8 waves, 32-col span each, FN=2, FM=1).
__device__ __forceinline__
void fwd_layer(half_t* __restrict__ Ah, half_t* __restrict__ Al,
               const half_t* __restrict__ Wh, const half_t* __restrict__ Wl,
               const float* __restrict__ bias, float* __restrict__ G,
               int K, bool writeH, int m0, int n0w, int lrow, int kgrp)
{
    f32x4 acc[2] = {};
    for (int k0 = 0; k0 < K; k0 += 32) {
        const int ko = k0 + kgrp * 8;
        const half8 ah = *(const half8*)&Ah[lrow * LDA + ko];
        const half8 al = *(const half8*)&Al[lrow * LDA + ko];
        #pragma unroll
        for (int fn = 0; fn < 2; ++fn) {
            const int col = n0w + fn * 16 + lrow;
            const half8 bh = *(const half8*)(Wh + (size_t)col * K + ko);
            const half8 bl = *(const half8*)(Wl + (size_t)col * K + ko);
            acc[fn] = __builtin_amdgcn_mfma_f32_16x16x32_f16(ah, bh, acc[fn], 0, 0, 0);
            acc[fn] = __builtin_amdgcn_mfma_f32_16x16x32_f16(ah, bl, acc[fn], 0, 0, 0);
            acc[fn] = __builtin_amdgcn_mfma_f32_16x16x32_f16(al, bh, acc[fn], 0, 0, 0);
        }
    }
    __syncthreads();                      // all reads of A done before overwrite
    #pragma unroll
    for (int fn = 0; fn < 2; ++fn) {
        const int col = n0w + fn * 16 + lrow;
        const float bc = bias[col];
        #pragma unroll
        for (int r = 0; r < 4; ++r) {
            const int row = kgrp * 4 + r;
            const float pre = acc[fn][r] + bc;
            float g, h;
            if (pre > 0.f) { g = 1.f; h = pre; }
            else           { g = __expf(pre); h = g - 1.f; }
            G[(size_t)(m0 + row) * D + col] = g;
            if (writeH) {
                const half_t hh = (half_t)h;
                Ah[row * LDA + col] = hh;
                Al[row * LDA + col] = (half_t)(h - (float)hh);
            }
        }
    }
    __syncthreads();
}

__global__ __launch_bounds__(512)
void fwd_fused(const float* __restrict__ x,
               const half_t* __restrict__ W1h, const half_t* __restrict__ W1l, const float* __restrict__ b1, float* __restrict__ G1,
               const half_t* __restrict__ W2h, const half_t* __restrict__ W2l, const float* __restrict__ b2, float* __restrict__ G2,
               const half_t* __restrict__ W3h, const half_t* __restrict__ W3l, const float* __restrict__ b3, float* __restrict__ G3,
               const half_t* __restrict__ W4h, const half_t* __restrict__ W4l, const float* __restrict__ b4, float* __restrict__ G4)
{
    __shared__ half_t Ah[16 * LDA];
    __shared__ half_t Al[16 * LDA];
    const int tid = threadIdx.x;
    const int m0 = blockIdx.x * 16;
    if (tid < 256) {   // load + split x [16][64]
        const int row = tid >> 4, c4 = (tid & 15) * 4;
        const float4 v = *(const float4*)(x + (size_t)(m0 + row) * 64 + c4);
        const float vv[4] = {v.x, v.y, v.z, v.w};
        #pragma unroll
        for (int j = 0; j < 4; ++j) {
            const half_t h = (half_t)vv[j];
            Ah[row * LDA + c4 + j] = h;
            Al[row * LDA + c4 + j] = (half_t)(vv[j] - (float)h);
        }
    }
    __syncthreads();
    const int lane = tid & 63, lrow = lane & 15, kgrp = lane >> 4;
    const int n0w = (tid >> 6) * 32;
    fwd_layer(Ah, Al, W1h, W1l, b1, G1,  64, true,  m0, n0w, lrow, kgrp);
    fwd_layer(Ah, Al, W2h, W2l, b2, G2, 256, true,  m0, n0w, lrow, kgrp);
    fwd_layer(Ah, Al, W3h, W3l, b3, G3, 256, true,  m0, n0w, lrow, kgrp);
    fwd_layer(Ah, Al, W4h, W4l, b4, G4, 256, false, m0, n0w, lrow, kgrp);
}

// ---------------- fused backward ----------------
// Block = 16 samples, 512 threads. C rows laid out as row = o*16 + s
// (o = output index 0..2, s = sample-in-block 0..15): G-scale of a D-fragment
// is then independent of the row-fragment index -> 8 prefetched G loads/lane.
__device__ __forceinline__
void bwd_mid(half_t* __restrict__ Ch, half_t* __restrict__ Cl,
             const half_t* __restrict__ Th, const half_t* __restrict__ Tl,
             const float* __restrict__ Gsc, int m0s, int n0w, int lrow, int kgrp)
{
    // prefetch G[s = kgrp*4+r][col] — hides under the MFMA k-loop
    float gpre[2][4];
    #pragma unroll
    for (int fn = 0; fn < 2; ++fn) {
        const int col = n0w + fn * 16 + lrow;
        #pragma unroll
        for (int r = 0; r < 4; ++r)
            gpre[fn][r] = Gsc[(size_t)(m0s + kgrp * 4 + r) * D + col];
    }
    f32x4 acc[3][2] = {};
    for (int k0 = 0; k0 < 256; k0 += 32) {
        const int ko = k0 + kgrp * 8;
        half8 ah[3], al[3];
        #pragma unroll
        for (int fm = 0; fm < 3; ++fm) {
            ah[fm] = *(const half8*)&Ch[(fm * 16 + lrow) * LDA + ko];
            al[fm] = *(const half8*)&Cl[(fm * 16 + lrow) * LDA + ko];
        }
        #pragma unroll
        for (int fn = 0; fn < 2; ++fn) {
            const int col = n0w + fn * 16 + lrow;
            const half8 bh = *(const half8*)(Th + (size_t)col * 256 + ko);
            const half8 bl = *(const half8*)(Tl + (size_t)col * 256 + ko);
            #pragma unroll
            for (int fm = 0; fm < 3; ++fm) {
                acc[fm][fn] = __builtin_amdgcn_mfma_f32_16x16x32_f16(ah[fm], bh, acc[fm][fn], 0, 0, 0);
                acc[fm][fn] = __builtin_amdgcn_mfma_f32_16x16x32_f16(ah[fm], bl, acc[fm][fn], 0, 0, 0);
                acc[fm][fn] = __builtin_amdgcn_mfma_f32_16x16x32_f16(al[fm], bh, acc[fm][fn], 0, 0, 0);
            }
        }
    }
    __syncthreads();
    #pragma unroll
    for (int fn = 0; fn < 2; ++fn) {
        const int col = n0w + fn * 16 + lrow;
        #pragma unroll
        for (int fm = 0; fm < 3; ++fm) {
            #pragma unroll
            for (int r = 0; r < 4; ++r) {
                const int row = fm * 16 + kgrp * 4 + r;
                const float v = acc[fm][fn][r] * gpre[fn][r];
                const half_t h = (half_t)v;
                Ch[row * LDA + col] = h;
                Cl[row * LDA + col] = (half_t)(v - (float)h);
            }
        }
    }
    __syncthreads();
}

__global__ __launch_bounds__(512)
void bwd_fused(const float* __restrict__ G4, const float* __restrict__ W5,
               const half_t* __restrict__ T4h, const half_t* __restrict__ T4l, const float* __restrict__ G3,
               const half_t* __restrict__ T3h, const half_t* __restrict__ T3l, const float* __restrict__ G2,
               const half_t* __restrict__ T2h, const half_t* __restrict__ T2l, const float* __restrict__ G1,
               const half_t* __restrict__ T1h, const half_t* __restrict__ T1l,
               float* __restrict__ out)
{
    __shared__ half_t Ch[48 * LDA];
    __shared__ half_t Cl[48 * LDA];
    const int tid = threadIdx.x;
    const int m0s = blockIdx.x * 16;        // sample base

    // expand: C0[o*16+s][k] = W5[o][k] * G4[m0s+s][k]
    #pragma unroll
    for (int t = 0; t < 6; ++t) {
        const int idx = tid + t * 512;       // 0..3071 float4s
        const int r = idx >> 6;              // row 0..47
        const int k4 = (idx & 63) * 4;
        const int o = r >> 4, s = r & 15;
        const float4 g = *(const float4*)(G4 + (size_t)(m0s + s) * D + k4);
        const float4 w = *(const float4*)(W5 + (size_t)o * D + k4);
        const float vv[4] = {g.x * w.x, g.y * w.y, g.z * w.z, g.w * w.w};
        #pragma unroll
        for (int j = 0; j < 4; ++j) {
            const half_t h = (half_t)vv[j];
            Ch[r * LDA + k4 + j] = h;
            Cl[r * LDA + k4 + j] = (half_t)(vv[j] - (float)h);
        }
    }
    __syncthreads();

    const int lane = tid & 63, lrow = lane & 15, kgrp = lane >> 4;
    const int wave = tid >> 6;
    const int n0w = wave * 32;

    bwd_mid(Ch, Cl, T4h, T4l, G3, m0s, n0w, lrow, kgrp);
    bwd_mid(Ch, Cl, T3h, T3l, G2, m0s, n0w, lrow, kgrp);
    bwd_mid(Ch, Cl, T2h, T2l, G1, m0s, n0w, lrow, kgrp);

    // final: [48][256] @ T1[64][256]^T -> out rows (m0s+s)*3+o, cols 64.
    // waves 0-3: o in {0,1}; waves 4-7: o = 2.  col group = (wave&3)*16.
    {
        const int fnf  = wave & 3;
        const int colf = fnf * 16 + lrow;
        if (wave < 4) {
            f32x4 acc[2] = {};
            for (int k0 = 0; k0 < 256; k0 += 32) {
                const int ko = k0 + kgrp * 8;
                const half8 bh = *(const half8*)(T1h + (size_t)colf * 256 + ko);
                const half8 bl = *(const half8*)(T1l + (size_t)colf * 256 + ko);
                #pragma unroll
                for (int fm = 0; fm < 2; ++fm) {
                    const half8 ah = *(const half8*)&Ch[(fm * 16 + lrow) * LDA + ko];
                    const half8 al = *(const half8*)&Cl[(fm * 16 + lrow) * LDA + ko];
                    acc[fm] = __builtin_amdgcn_mfma_f32_16x16x32_f16(ah, bh, acc[fm], 0, 0, 0);
                    acc[fm] = __builtin_amdgcn_mfma_f32_16x16x32_f16(ah, bl, acc[fm], 0, 0, 0);
                    acc[fm] = __builtin_amdgcn_mfma_f32_16x16x32_f16(al, bh, acc[fm], 0, 0, 0);
                }
            }
            #pragma unroll
            for (int fm = 0; fm < 2; ++fm)
                #pragma unroll
                for (int r = 0; r < 4; ++r) {
                    const int s = kgrp * 4 + r;
                    out[((size_t)(m0s + s) * 3 + fm) * 64 + colf] = acc[fm][r];
                }
        } else {
            f32x4 acc = {};
            for (int k0 = 0; k0 < 256; k0 += 32) {
                const int ko = k0 + kgrp * 8;
                const half8 bh = *(const half8*)(T1h + (size_t)colf * 256 + ko);
                const half8 bl = *(const half8*)(T1l + (size_t)colf * 256 + ko);
                const half8 ah = *(const half8*)&Ch[(2 * 16 + lrow) * LDA + ko];
                const half8 al = *(const half8*)&Cl[(2 * 16 + lrow) * LDA + ko];
                acc = __builtin_amdgcn_mfma_f32_16x16x32_f16(ah, bh, acc, 0, 0, 0);
                acc = __builtin_amdgcn_mfma_f32_16x16x32_f16(ah, bl, acc, 0, 0, 0);
                acc = __builtin_amdgcn_mfma_f32_16x16x32_f16(al, bh, acc, 0, 0, 0);
            }
            #pragma unroll
            for (int r = 0; r < 4; ++r) {
                const int s = kgrp * 4 + r;
                out[((size_t)(m0s + s) * 3 + 2) * 64 + colf] = acc[r];
            }
        }
    }
}

extern "C" void kernel_launch(void* const* d_in, const int* in_sizes, int n_in,
                              void* d_out, int out_size, void* d_ws, size_t ws_size,
                              hipStream_t stream)
{
    const float* x  = (const float*)d_in[0];
    const float* W1 = (const float*)d_in[1];
    const float* b1 = (const float*)d_in[2];
    const float* W2 = (const float*)d_in[3];
    const float* b2 = (const float*)d_in[4];
    const float* W3 = (const float*)d_in[5];
    const float* b3 = (const float*)d_in[6];
    const float* W4 = (const float*)d_in[7];
    const float* b4 = (const float*)d_in[8];
    const float* W5 = (const float*)d_in[9];

    // ---- workspace carve (~34 MB) ----
    char* p = (char*)d_ws;
    float* G1 = (float*)p; p += (size_t)Bsz * D * 4;
    float* G2 = (float*)p; p += (size_t)Bsz * D * 4;
    float* G3 = (float*)p; p += (size_t)Bsz * D * 4;
    float* G4 = (float*)p; p += (size_t)Bsz * D * 4;
    half_t* W1h = (half_t*)p; p += 256 * 64 * 2;
    half_t* W1l = (half_t*)p; p += 256 * 64 * 2;
    half_t* T1h = (half_t*)p; p += 64 * 256 * 2;
    half_t* T1l = (half_t*)p; p += 64 * 256 * 2;
    half_t* W2h = (half_t*)p; p += 256 * 256 * 2;
    half_t* W2l = (half_t*)p; p += 256 * 256 * 2;
    half_t* T2h = (half_t*)p; p += 256 * 256 * 2;
    half_t* T2l = (half_t*)p; p += 256 * 256 * 2;
    half_t* W3h = (half_t*)p; p += 256 * 256 * 2;
    half_t* W3l = (half_t*)p; p += 256 * 256 * 2;
    half_t* T3h = (half_t*)p; p += 256 * 256 * 2;
    half_t* T3l = (half_t*)p; p += 256 * 256 * 2;
    half_t* W4h = (half_t*)p; p += 256 * 256 * 2;
    half_t* W4l = (half_t*)p; p += 256 * 256 * 2;
    half_t* T4h = (half_t*)p; p += 256 * 256 * 2;
    half_t* T4l = (half_t*)p; p += 256 * 256 * 2;

    prep_split<<<208, 256, 0, stream>>>(W1, W2, W3, W4,
        W1h, W1l, T1h, T1l, W2h, W2l, T2h, T2l,
        W3h, W3l, T3h, T3l, W4h, W4l, T4h, T4l);

    fwd_fused<<<Bsz / 16, 512, 0, stream>>>(x,
        W1h, W1l, b1, G1,  W2h, W2l, b2, G2,
        W3h, W3l, b3, G3,  W4h, W4l, b4, G4);

    bwd_fused<<<Bsz / 16, 512, 0, stream>>>(G4, W5,
        T4h, T4l, G3,  T3h, T3l, G2,  T2h, T2l, G1,
        T1h, T1l, (float*)d_out);
}

// Round 5
// 108.875 us; speedup vs baseline: 2.1497x; 1.0631x over previous
//
#include <hip/hip_runtime.h>
#include <cstdint>
#include <cstddef>

// NetGrad J = W5 D4 W4 D3 W3 D2 W2 D1 W1, output [B,3,64].
// Single fused kernel per 16-sample block: fwd chain (H in LDS, G1..G4 in
// REGISTERS - same lane mapping as bwd consumer) then bwd chain (48-row C in
// LDS, row layout o*16+s). MFMA f16 hi/lo split (hh + hl + lh), fp32 accum.
// 512 threads = 8 waves, each owning a 32-col span (fn=2 fragments).

typedef _Float16 half_t;
typedef __attribute__((ext_vector_type(8))) _Float16 half8;
typedef __attribute__((ext_vector_type(4))) float f32x4;

constexpr int Bsz = 8192;
constexpr int D   = 256;
constexpr int LDA = 264;          // LDS row stride in halves (528 B)

// ---------------- prep: split (native) + transpose-split all weights ----------------
__global__ __launch_bounds__(256)
void prep_split(const float* __restrict__ W1, const float* __restrict__ W2,
                const float* __restrict__ W3, const float* __restrict__ W4,
                half_t* W1h, half_t* W1l, half_t* T1h, half_t* T1l,
                half_t* W2h, half_t* W2l, half_t* T2h, half_t* T2l,
                half_t* W3h, half_t* W3l, half_t* T3h, half_t* T3l,
                half_t* W4h, half_t* W4l, half_t* T4h, half_t* T4l)
{
    __shared__ float tile[32][33];
    const int bid = blockIdx.x;
    const float* src; half_t *sh, *sl, *th, *tl; int C, bx, by;
    if (bid < 16) {
        src = W1; sh = W1h; sl = W1l; th = T1h; tl = T1l;
        C = 64; bx = bid & 1; by = bid >> 1;
    } else {
        const int q = bid - 16, j = q >> 6, lo = q & 63;
        bx = lo & 7; by = lo >> 3; C = 256;
        if (j == 0)      { src = W2; sh = W2h; sl = W2l; th = T2h; tl = T2l; }
        else if (j == 1) { src = W3; sh = W3h; sl = W3l; th = T3h; tl = T3l; }
        else             { src = W4; sh = W4h; sl = W4l; th = T4h; tl = T4l; }
    }
    const int R = 256;
    const int tx = threadIdx.x & 31, ty = threadIdx.x >> 5;
    #pragma unroll
    for (int i = 0; i < 32; i += 8) {
        const size_t o = (size_t)(by * 32 + ty + i) * C + bx * 32 + tx;
        const float v = src[o];
        tile[ty + i][tx] = v;
        const half_t h = (half_t)v;
        sh[o] = h; sl[o] = (half_t)(v - (float)h);
    }
    __syncthreads();
    #pragma unroll
    for (int i = 0; i < 32; i += 8) {
        const float v = tile[tx][ty + i];
        const half_t h = (half_t)v;
        const size_t o = (size_t)(bx * 32 + ty + i) * R + by * 32 + tx;
        th[o] = h; tl[o] = (half_t)(v - (float)h);
    }
}

// ---------------- fwd layer: pre = H @ W^T + b; G -> regs; H' = elu -> LDS ----------------
__device__ __forceinline__
void fwd_layer(half_t* __restrict__ Ah, half_t* __restrict__ Al,
               const half_t* __restrict__ Wh, const half_t* __restrict__ Wl,
               const float* __restrict__ bias, float gout[2][4],
               int K, bool writeH, int n0w, int lrow, int kgrp)
{
    f32x4 acc[2] = {};
    for (int k0 = 0; k0 < K; k0 += 32) {
        const int ko = k0 + kgrp * 8;
        const half8 ah = *(const half8*)&Ah[lrow * LDA + ko];
        const half8 al = *(const half8*)&Al[lrow * LDA + ko];
        #pragma unroll
        for (int fn = 0; fn < 2; ++fn) {
            const int col = n0w + fn * 16 + lrow;
            const half8 bh = *(const half8*)(Wh + (size_t)col * K + ko);
            const half8 bl = *(const half8*)(Wl + (size_t)col * K + ko);
            acc[fn] = __builtin_amdgcn_mfma_f32_16x16x32_f16(ah, bh, acc[fn], 0, 0, 0);
            acc[fn] = __builtin_amdgcn_mfma_f32_16x16x32_f16(ah, bl, acc[fn], 0, 0, 0);
            acc[fn] = __builtin_amdgcn_mfma_f32_16x16x32_f16(al, bh, acc[fn], 0, 0, 0);
        }
    }
    __syncthreads();                      // all reads of A done before overwrite
    #pragma unroll
    for (int fn = 0; fn < 2; ++fn) {
        const int col = n0w + fn * 16 + lrow;
        const float bc = bias[col];
        #pragma unroll
        for (int r = 0; r < 4; ++r) {
            const int row = kgrp * 4 + r;
            const float pre = acc[fn][r] + bc;
            float g, h;
            if (pre > 0.f) { g = 1.f; h = pre; }
            else           { g = __expf(pre); h = g - 1.f; }
            gout[fn][r] = g;
            if (writeH) {
                const half_t hh = (half_t)h;
                Ah[row * LDA + col] = hh;
                Al[row * LDA + col] = (half_t)(h - (float)hh);
            }
        }
    }
    __syncthreads();
}

// ---------------- bwd mid step: C' = (C @ T^T) * G  (G from regs) ----------------
__device__ __forceinline__
void bwd_mid(half_t* __restrict__ Ch, half_t* __restrict__ Cl,
             const half_t* __restrict__ Th, const half_t* __restrict__ Tl,
             const float gpre[2][4], int n0w, int lrow, int kgrp)
{
    f32x4 acc[3][2] = {};
    for (int k0 = 0; k0 < 256; k0 += 32) {
        const int ko = k0 + kgrp * 8;
        half8 ah[3], al[3];
        #pragma unroll
        for (int fm = 0; fm < 3; ++fm) {
            ah[fm] = *(const half8*)&Ch[(fm * 16 + lrow) * LDA + ko];
            al[fm] = *(const half8*)&Cl[(fm * 16 + lrow) * LDA + ko];
        }
        #pragma unroll
        for (int fn = 0; fn < 2; ++fn) {
            const int col = n0w + fn * 16 + lrow;
            const half8 bh = *(const half8*)(Th + (size_t)col * 256 + ko);
            const half8 bl = *(const half8*)(Tl + (size_t)col * 256 + ko);
            #pragma unroll
            for (int fm = 0; fm < 3; ++fm) {
                acc[fm][fn] = __builtin_amdgcn_mfma_f32_16x16x32_f16(ah[fm], bh, acc[fm][fn], 0, 0, 0);
                acc[fm][fn] = __builtin_amdgcn_mfma_f32_16x16x32_f16(ah[fm], bl, acc[fm][fn], 0, 0, 0);
                acc[fm][fn] = __builtin_amdgcn_mfma_f32_16x16x32_f16(al[fm], bh, acc[fm][fn], 0, 0, 0);
            }
        }
    }
    __syncthreads();
    #pragma unroll
    for (int fn = 0; fn < 2; ++fn) {
        const int col = n0w + fn * 16 + lrow;
        #pragma unroll
        for (int fm = 0; fm < 3; ++fm) {
            #pragma unroll
            for (int r = 0; r < 4; ++r) {
                const int row = fm * 16 + kgrp * 4 + r;
                const float v = acc[fm][fn][r] * gpre[fn][r];
                const half_t h = (half_t)v;
                Ch[row * LDA + col] = h;
                Cl[row * LDA + col] = (half_t)(v - (float)h);
            }
        }
    }
    __syncthreads();
}

// ---------------- fully fused forward+backward ----------------
__global__ __launch_bounds__(512, 4)
void netgrad_fused(const float* __restrict__ x,
                   const half_t* __restrict__ W1h, const half_t* __restrict__ W1l, const float* __restrict__ b1,
                   const half_t* __restrict__ W2h, const half_t* __restrict__ W2l, const float* __restrict__ b2,
                   const half_t* __restrict__ W3h, const half_t* __restrict__ W3l, const float* __restrict__ b3,
                   const half_t* __restrict__ W4h, const half_t* __restrict__ W4l, const float* __restrict__ b4,
                   const float* __restrict__ W5,
                   const half_t* __restrict__ T4h, const half_t* __restrict__ T4l,
                   const half_t* __restrict__ T3h, const half_t* __restrict__ T3l,
                   const half_t* __restrict__ T2h, const half_t* __restrict__ T2l,
                   const half_t* __restrict__ T1h, const half_t* __restrict__ T1l,
                   float* __restrict__ out)
{
    __shared__ half_t Ch[48 * LDA];
    __shared__ half_t Cl[48 * LDA];
    half_t* Ah = Ch;                       // fwd H chain aliases C rows 0..15
    half_t* Al = Cl;
    const int tid = threadIdx.x;
    const int m0s = blockIdx.x * 16;       // sample base

    // ---- load + split x [16][64] ----
    if (tid < 256) {
        const int row = tid >> 4, c4 = (tid & 15) * 4;
        const float4 v = *(const float4*)(x + (size_t)(m0s + row) * 64 + c4);
        const float vv[4] = {v.x, v.y, v.z, v.w};
        #pragma unroll
        for (int j = 0; j < 4; ++j) {
            const half_t h = (half_t)vv[j];
            Ah[row * LDA + c4 + j] = h;
            Al[row * LDA + c4 + j] = (half_t)(vv[j] - (float)h);
        }
    }
    __syncthreads();

    const int lane = tid & 63, lrow = lane & 15, kgrp = lane >> 4;
    const int wave = tid >> 6;
    const int n0w = wave * 32;

    // ---- forward: G_i stay in registers (lane mapping == bwd consumer) ----
    float G1r[2][4], G2r[2][4], G3r[2][4], G4r[2][4];
    fwd_layer(Ah, Al, W1h, W1l, b1, G1r,  64, true,  n0w, lrow, kgrp);
    fwd_layer(Ah, Al, W2h, W2l, b2, G2r, 256, true,  n0w, lrow, kgrp);
    fwd_layer(Ah, Al, W3h, W3l, b3, G3r, 256, true,  n0w, lrow, kgrp);
    fwd_layer(Ah, Al, W4h, W4l, b4, G4r, 256, false, n0w, lrow, kgrp);

    // ---- expand: C0[o*16+s][k] = W5[o][k] * G4[s][k], G4 from regs ----
    #pragma unroll
    for (int fn = 0; fn < 2; ++fn) {
        const int k = n0w + fn * 16 + lrow;
        float w5v[3];
        #pragma unroll
        for (int o = 0; o < 3; ++o) w5v[o] = W5[o * 256 + k];
        #pragma unroll
        for (int o = 0; o < 3; ++o)
            #pragma unroll
            for (int r = 0; r < 4; ++r) {
                const int s = kgrp * 4 + r;
                const float v = w5v[o] * G4r[fn][r];
                const half_t h = (half_t)v;
                Ch[(o * 16 + s) * LDA + k] = h;
                Cl[(o * 16 + s) * LDA + k] = (half_t)(v - (float)h);
            }
    }
    __syncthreads();

    // ---- backward chain ----
    bwd_mid(Ch, Cl, T4h, T4l, G3r, n0w, lrow, kgrp);
    bwd_mid(Ch, Cl, T3h, T3l, G2r, n0w, lrow, kgrp);
    bwd_mid(Ch, Cl, T2h, T2l, G1r, n0w, lrow, kgrp);

    // ---- final: [48][256] @ T1[64][256]^T -> out rows (m0s+s)*3+o ----
    {
        const int fnf  = wave & 3;
        const int colf = fnf * 16 + lrow;
        if (wave < 4) {
            f32x4 acc[2] = {};
            for (int k0 = 0; k0 < 256; k0 += 32) {
                const int ko = k0 + kgrp * 8;
                const half8 bh = *(const half8*)(T1h + (size_t)colf * 256 + ko);
                const half8 bl = *(const half8*)(T1l + (size_t)colf * 256 + ko);
                #pragma unroll
                for (int fm = 0; fm < 2; ++fm) {
                    const half8 ah = *(const half8*)&Ch[(fm * 16 + lrow) * LDA + ko];
                    const half8 al = *(const half8*)&Cl[(fm * 16 + lrow) * LDA + ko];
                    acc[fm] = __builtin_amdgcn_mfma_f32_16x16x32_f16(ah, bh, acc[fm], 0, 0, 0);
                    acc[fm] = __builtin_amdgcn_mfma_f32_16x16x32_f16(ah, bl, acc[fm], 0, 0, 0);
                    acc[fm] = __builtin_amdgcn_mfma_f32_16x16x32_f16(al, bh, acc[fm], 0, 0, 0);
                }
            }
            #pragma unroll
            for (int fm = 0; fm < 2; ++fm)
                #pragma unroll
                for (int r = 0; r < 4; ++r) {
                    const int s = kgrp * 4 + r;
                    out[((size_t)(m0s + s) * 3 + fm) * 64 + colf] = acc[fm][r];
                }
        } else {
            f32x4 acc = {};
            for (int k0 = 0; k0 < 256; k0 += 32) {
                const int ko = k0 + kgrp * 8;
                const half8 bh = *(const half8*)(T1h + (size_t)colf * 256 + ko);
                const half8 bl = *(const half8*)(T1l + (size_t)colf * 256 + ko);
                const half8 ah = *(const half8*)&Ch[(2 * 16 + lrow) * LDA + ko];
                const half8 al = *(const half8*)&Cl[(2 * 16 + lrow) * LDA + ko];
                acc = __builtin_amdgcn_mfma_f32_16x16x32_f16(ah, bh, acc, 0, 0, 0);
                acc = __builtin_amdgcn_mfma_f32_16x16x32_f16(ah, bl, acc, 0, 0, 0);
                acc = __builtin_amdgcn_mfma_f32_16x16x32_f16(al, bh, acc, 0, 0, 0);
            }
            #pragma unroll
            for (int r = 0; r < 4; ++r) {
                const int s = kgrp * 4 + r;
                out[((size_t)(m0s + s) * 3 + 2) * 64 + colf] = acc[r];
            }
        }
    }
}

extern "C" void kernel_launch(void* const* d_in, const int* in_sizes, int n_in,
                              void* d_out, int out_size, void* d_ws, size_t ws_size,
                              hipStream_t stream)
{
    const float* x  = (const float*)d_in[0];
    const float* W1 = (const float*)d_in[1];
    const float* b1 = (const float*)d_in[2];
    const float* W2 = (const float*)d_in[3];
    const float* b2 = (const float*)d_in[4];
    const float* W3 = (const float*)d_in[5];
    const float* b3 = (const float*)d_in[6];
    const float* W4 = (const float*)d_in[7];
    const float* b4 = (const float*)d_in[8];
    const float* W5 = (const float*)d_in[9];

    // ---- workspace carve (~2.6 MB: weight splits only) ----
    char* p = (char*)d_ws;
    half_t* W1h = (half_t*)p; p += 256 * 64 * 2;
    half_t* W1l = (half_t*)p; p += 256 * 64 * 2;
    half_t* T1h = (half_t*)p; p += 64 * 256 * 2;
    half_t* T1l = (half_t*)p; p += 64 * 256 * 2;
    half_t* W2h = (half_t*)p; p += 256 * 256 * 2;
    half_t* W2l = (half_t*)p; p += 256 * 256 * 2;
    half_t* T2h = (half_t*)p; p += 256 * 256 * 2;
    half_t* T2l = (half_t*)p; p += 256 * 256 * 2;
    half_t* W3h = (half_t*)p; p += 256 * 256 * 2;
    half_t* W3l = (half_t*)p; p += 256 * 256 * 2;
    half_t* T3h = (half_t*)p; p += 256 * 256 * 2;
    half_t* T3l = (half_t*)p; p += 256 * 256 * 2;
    half_t* W4h = (half_t*)p; p += 256 * 256 * 2;
    half_t* W4l = (half_t*)p; p += 256 * 256 * 2;
    half_t* T4h = (half_t*)p; p += 256 * 256 * 2;
    half_t* T4l = (half_t*)p; p += 256 * 256 * 2;

    prep_split<<<208, 256, 0, stream>>>(W1, W2, W3, W4,
        W1h, W1l, T1h, T1l, W2h, W2l, T2h, T2l,
        W3h, W3l, T3h, T3l, W4h, W4l, T4h, T4l);

    netgrad_fused<<<Bsz / 16, 512, 0, stream>>>(x,
        W1h, W1l, b1,  W2h, W2l, b2,  W3h, W3l, b3,  W4h, W4l, b4,
        W5,  T4h, T4l, T3h, T3l, T2h, T2l, T1h, T1l,
        (float*)d_out);
}